// Round 1
// baseline (627.937 us; speedup 1.0000x reference)
//
#include <hip/hip_runtime.h>
#include <stdint.h>

typedef unsigned short ushort_t;
typedef __attribute__((ext_vector_type(8))) short bf16x8;
typedef __attribute__((ext_vector_type(4))) float f32x4;
typedef __attribute__((ext_vector_type(4))) unsigned short us4;

static __device__ __forceinline__ unsigned short f2bf(float f) {
  union { float f; uint32_t u; } v; v.f = f;
  uint32_t u = v.u;
  u += 0x7FFFu + ((u >> 16) & 1u);
  return (unsigned short)(u >> 16);
}

static __device__ __forceinline__ float wredsum(float v) {
#pragma unroll
  for (int o = 32; o > 0; o >>= 1) v += __shfl_down(v, o, 64);
  return v;
}
static __device__ __forceinline__ float wredmax(float v) {
#pragma unroll
  for (int o = 32; o > 0; o >>= 1) v = fmaxf(v, __shfl_down(v, o, 64));
  return v;
}

// ---------------------------------------------------------------------------
// Weight fp32 -> bf16 conversion (Wq|Wk|Wv|Wp into one slab)
// ---------------------------------------------------------------------------
__global__ __launch_bounds__(256) void cvt_w(
    const float* __restrict__ Wq, const float* __restrict__ Wk,
    const float* __restrict__ Wv, const float* __restrict__ Wp,
    ushort_t* __restrict__ dst) {
  int m = blockIdx.y;
  const float* src = (m == 0) ? Wq : (m == 1) ? Wk : (m == 2) ? Wv : Wp;
  int i = blockIdx.x * 256 + threadIdx.x;  // float4 index, 16384 per matrix
  float4 v = ((const float4*)src)[i];
  us4 o;
  o.x = f2bf(v.x); o.y = f2bf(v.y); o.z = f2bf(v.z); o.w = f2bf(v.w);
  *(us4*)&dst[(size_t)m * 65536 + (size_t)i * 4] = o;
}

// ---------------------------------------------------------------------------
// GroupNorm stats: one block per (sel, b, g). mean + rstd over 8ch x 2304 px.
// ---------------------------------------------------------------------------
__global__ __launch_bounds__(256) void gn_stats(
    const float* __restrict__ x1, const float* __restrict__ x2,
    float* __restrict__ stats) {
  const int sel = blockIdx.x >> 8;
  const int bg = blockIdx.x & 255;  // b*32 + g
  const float* x = (sel ? x2 : x1) + (size_t)bg * 8 * 2304;
  float s = 0.f, ss = 0.f;
  for (int i = threadIdx.x; i < 4608; i += 256) {
    float4 v = ((const float4*)x)[i];
    s += v.x + v.y + v.z + v.w;
    ss += v.x * v.x + v.y * v.y + v.z * v.z + v.w * v.w;
  }
  s = wredsum(s);
  ss = wredsum(ss);
  __shared__ float ls[8];
  int wave = threadIdx.x >> 6, lane = threadIdx.x & 63;
  if (lane == 0) { ls[wave] = s; ls[4 + wave] = ss; }
  __syncthreads();
  if (threadIdx.x == 0) {
    float S = ls[0] + ls[1] + ls[2] + ls[3];
    float SS = ls[4] + ls[5] + ls[6] + ls[7];
    float mu = S * (1.f / 18432.f);
    float var = SS * (1.f / 18432.f) - mu * mu;
    stats[(sel * 256 + bg) * 2] = mu;
    stats[(sel * 256 + bg) * 2 + 1] = rsqrtf(var + 1e-6f);
  }
}

// ---------------------------------------------------------------------------
// GroupNorm apply + transpose: writes h_t[b][n][c] bf16. Block = (ntile,b,sel).
// ---------------------------------------------------------------------------
__global__ __launch_bounds__(256) void gn_apply(
    const float* __restrict__ x1, const float* __restrict__ x2,
    const float* __restrict__ gamma, const float* __restrict__ beta,
    const float* __restrict__ stats,
    ushort_t* __restrict__ h1t, ushort_t* __restrict__ h2t) {
  const int sel = blockIdx.z, b = blockIdx.y, nt = blockIdx.x;
  const int n0 = nt * 64;
  const float* x = (sel ? x2 : x1) + (size_t)b * 256 * 2304;
  ushort_t* ht = (sel ? h2t : h1t) + (size_t)b * 2304 * 256;
  const float* st = stats + (sel * 8 + b) * 64;  // 32 groups * 2
  __shared__ ushort_t lt[64 * 260];
#pragma unroll 4
  for (int it = 0; it < 64; ++it) {
    int flat = it * 256 + threadIdx.x;
    int c = flat >> 6, nn = flat & 63;
    float v = x[(size_t)c * 2304 + n0 + nn];
    int g = c >> 3;
    float mu = st[g * 2], rstd = st[g * 2 + 1];
    lt[nn * 260 + c] = f2bf((v - mu) * rstd * gamma[c] + beta[c]);
  }
  __syncthreads();
#pragma unroll 4
  for (int it = 0; it < 16; ++it) {
    int flat4 = it * 256 + threadIdx.x;
    int nn = flat4 >> 6, cq = flat4 & 63;
    us4 vv = *(const us4*)&lt[nn * 260 + cq * 4];
    *(us4*)&ht[(size_t)(n0 + nn) * 256 + cq * 4] = vv;
  }
}

// ---------------------------------------------------------------------------
// Softmax row stats over materialized scores: one block per row.
// ---------------------------------------------------------------------------
__global__ __launch_bounds__(256) void rowstats(
    const float* __restrict__ w, float* __restrict__ rmax,
    float* __restrict__ rsumr) {
  const size_t row = blockIdx.x;
  const float* r = w + row * 2304;
  float mx = -3.4e38f;
  for (int i = threadIdx.x; i < 576; i += 256) {
    float4 v = ((const float4*)r)[i];
    mx = fmaxf(fmaxf(fmaxf(mx, v.x), v.y), fmaxf(v.z, v.w));
  }
  mx = wredmax(mx);
  __shared__ float ls[4];
  __shared__ float smax;
  int wave = threadIdx.x >> 6, lane = threadIdx.x & 63;
  if (lane == 0) ls[wave] = mx;
  __syncthreads();
  if (threadIdx.x == 0) smax = fmaxf(fmaxf(ls[0], ls[1]), fmaxf(ls[2], ls[3]));
  __syncthreads();
  mx = smax;
  float s = 0.f;
  for (int i = threadIdx.x; i < 576; i += 256) {
    float4 v = ((const float4*)r)[i];
    s += __expf(v.x - mx) + __expf(v.y - mx) + __expf(v.z - mx) +
         __expf(v.w - mx);
  }
  s = wredsum(s);
  __shared__ float ls2[4];
  if (lane == 0) ls2[wave] = s;
  __syncthreads();
  if (threadIdx.x == 0) {
    float S = ls2[0] + ls2[1] + ls2[2] + ls2[3];
    rmax[row] = mx;
    rsumr[row] = 1.f / S;
  }
}

// ---------------------------------------------------------------------------
// Generic both-K-contiguous MFMA GEMM.  C[m][n] = sum_k A[m][k]*B[n][k].
// 128x128 tile, BK=32, 256 threads (4 waves, 2x2 of 64x64), 16x16x32 bf16.
// MODE_A : 0 = A bf16 [M][K] via global_load_lds
//          1 = A fp32 scores; softmax(exp(w-rmax)*rsumr) fused into staging
// MODE_OUT: 0 bf16 +bias[col] | 1 bf16 +bias[row] | 2 bf16
//           3 fp32 = scale*acc | 4 fp32 += scale*acc
//           5 fp32 = acc + bias[row] + res[row][col]
// ---------------------------------------------------------------------------
template <int MODE_A, int MODE_OUT>
__global__ __launch_bounds__(256) void gemm_bt(
    const void* __restrict__ Av, const ushort_t* __restrict__ Bv,
    void* __restrict__ Cv, int M, int N, int K, long sA, long sB, long sC,
    const float* __restrict__ bias, const float* __restrict__ res, long sRes,
    const float* __restrict__ rmax, const float* __restrict__ rsumr, int sRow,
    float scale) {
  __shared__ ushort_t lA[128 * 32];
  __shared__ ushort_t lB[128 * 32];
  const int tid = threadIdx.x;
  const int lane = tid & 63, wave = tid >> 6;
  const int wm = wave >> 1, wn = wave & 1;
  const int bz = blockIdx.z;
  const int bM = blockIdx.x * 128, bN = blockIdx.y * 128;

  const ushort_t* B = Bv + (size_t)bz * sB + (size_t)bN * K;
  const ushort_t* Ab = nullptr;
  const float* Af = nullptr;
  if (MODE_A == 0)
    Ab = (const ushort_t*)Av + (size_t)bz * sA + (size_t)bM * K;
  else
    Af = (const float*)Av + (size_t)bz * sA + (size_t)bM * K;

  float mxv[4], rsv[4];
  if (MODE_A == 1) {
    const float* rm = rmax + (size_t)bz * sRow + bM;
    const float* rs = rsumr + (size_t)bz * sRow + bM;
#pragma unroll
    for (int i = 0; i < 4; ++i) {
      int row = i * 32 + (tid >> 3);
      mxv[i] = rm[row];
      rsv[i] = rs[row];
    }
  }

  f32x4 acc[4][4];
#pragma unroll
  for (int m = 0; m < 4; ++m)
#pragma unroll
    for (int n = 0; n < 4; ++n) acc[m][n] = (f32x4){0.f, 0.f, 0.f, 0.f};

  const int nK = K >> 5;
  for (int kt = 0; kt < nK; ++kt) {
    __syncthreads();
// stage B tile [128 cols][32 k] bf16, linear, via global_load_lds 16B
#pragma unroll
    for (int i = 0; i < 2; ++i) {
      int c = i * 256 + tid;
      int row = c >> 2, cb = (c & 3) * 8;
      const ushort_t* src = B + (size_t)row * K + kt * 32 + cb;
      __builtin_amdgcn_global_load_lds(
          (const __attribute__((address_space(1))) uint32_t*)src,
          (__attribute__((address_space(3))) uint32_t*)((char*)lB + i * 4096 +
                                                        wave * 1024),
          16, 0, 0);
    }
    if (MODE_A == 0) {
#pragma unroll
      for (int i = 0; i < 2; ++i) {
        int c = i * 256 + tid;
        int row = c >> 2, cb = (c & 3) * 8;
        const ushort_t* src = Ab + (size_t)row * K + kt * 32 + cb;
        __builtin_amdgcn_global_load_lds(
            (const __attribute__((address_space(1))) uint32_t*)src,
            (__attribute__((address_space(3))) uint32_t*)((char*)lA + i * 4096 +
                                                          wave * 1024),
            16, 0, 0);
      }
    } else {
// fp32 scores -> softmax probs -> bf16 into lA
#pragma unroll
      for (int i = 0; i < 4; ++i) {
        int row = i * 32 + (tid >> 3);
        int c4 = (tid & 7) * 4;
        float4 wv = *(const float4*)(Af + (size_t)row * K + kt * 32 + c4);
        float mx = mxv[i], rs = rsv[i];
        us4 p;
        p.x = f2bf(__expf(wv.x - mx) * rs);
        p.y = f2bf(__expf(wv.y - mx) * rs);
        p.z = f2bf(__expf(wv.z - mx) * rs);
        p.w = f2bf(__expf(wv.w - mx) * rs);
        *(us4*)&lA[row * 32 + c4] = p;
      }
    }
    __syncthreads();

    bf16x8 af[4], bfr[4];
    const int ko = (lane >> 4) * 8;
    const int rb = lane & 15;
#pragma unroll
    for (int m = 0; m < 4; ++m)
      af[m] = *(const bf16x8*)&lA[(wm * 64 + m * 16 + rb) * 32 + ko];
#pragma unroll
    for (int n = 0; n < 4; ++n)
      bfr[n] = *(const bf16x8*)&lB[(wn * 64 + n * 16 + rb) * 32 + ko];
#pragma unroll
    for (int m = 0; m < 4; ++m)
#pragma unroll
      for (int n = 0; n < 4; ++n)
        acc[m][n] =
            __builtin_amdgcn_mfma_f32_16x16x32_bf16(af[m], bfr[n], acc[m][n],
                                                    0, 0, 0);
  }

  // epilogue: D lane mapping col=lane&15, row=(lane>>4)*4+j
  const int r0 = (lane >> 4) * 4;
  const int c0 = lane & 15;
#pragma unroll
  for (int m = 0; m < 4; ++m) {
#pragma unroll
    for (int n = 0; n < 4; ++n) {
#pragma unroll
      for (int j = 0; j < 4; ++j) {
        int row = bM + wm * 64 + m * 16 + r0 + j;
        int col = bN + wn * 64 + n * 16 + c0;
        float v = acc[m][n][j];
        size_t idx = (size_t)row * N + col;
        if (MODE_OUT == 0) {
          ((ushort_t*)Cv + (size_t)bz * sC)[idx] = f2bf(v + bias[col]);
        } else if (MODE_OUT == 1) {
          ((ushort_t*)Cv + (size_t)bz * sC)[idx] = f2bf(v + bias[row]);
        } else if (MODE_OUT == 2) {
          ((ushort_t*)Cv + (size_t)bz * sC)[idx] = f2bf(v);
        } else if (MODE_OUT == 3) {
          ((float*)Cv + (size_t)bz * sC)[idx] = v * scale;
        } else if (MODE_OUT == 4) {
          float* p = (float*)Cv + (size_t)bz * sC + idx;
          *p = *p + v * scale;
        } else {
          ((float*)Cv + (size_t)bz * sC)[idx] =
              v + bias[row] + (res + (size_t)bz * sRes)[idx];
        }
      }
    }
  }
}

// ---------------------------------------------------------------------------
extern "C" void kernel_launch(void* const* d_in, const int* in_sizes, int n_in,
                              void* d_out, int out_size, void* d_ws,
                              size_t ws_size, hipStream_t stream) {
  (void)in_sizes; (void)n_in; (void)out_size;
  const float* x1 = (const float*)d_in[0];
  const float* x2 = (const float*)d_in[1];
  const float* gamma = (const float*)d_in[2];
  const float* beta = (const float*)d_in[3];
  const float* Wq = (const float*)d_in[4];
  const float* bq = (const float*)d_in[5];
  const float* Wk = (const float*)d_in[6];
  const float* bk = (const float*)d_in[7];
  const float* Wv = (const float*)d_in[8];
  const float* bv = (const float*)d_in[9];
  const float* Wp = (const float*)d_in[10];
  const float* bp = (const float*)d_in[11];
  float* out = (float*)d_out;

  const int C = 256, N = 2304;
  const long sH = (long)N * C;          // 589824 elems
  const long sW = (long)N * N;          // 5308416 elems
  const long sX = (long)C * N;          // per-batch x / out stride
  const size_t HE = (size_t)8 * N * C;  // bf16 buffer elems

  char* ws = (char*)d_ws;
  ushort_t* Wbf = (ushort_t*)ws;                    // 4 * 65536 bf16
  float* stats = (float*)(ws + 524288);             // 2*8*32*2 fp32
  ushort_t* h1t = (ushort_t*)(ws + 528384);
  ushort_t* h2t = h1t + HE;
  ushort_t* q1t = h2t + HE;
  ushort_t* k1t = q1t + HE;
  ushort_t* q2t = k1t + HE;
  ushort_t* k2t = q2t + HE;
  ushort_t* vB = k2t + HE;   // [b][c][n]
  ushort_t* attT = vB + HE;  // [b][n][c]
  float* rmax = (float*)(attT + HE);
  float* rsumr = rmax + (size_t)8 * N;
  float* wbuf = rsumr + (size_t)8 * N;  // chunked fp32 scores
  size_t used = (size_t)((char*)wbuf - ws);
  size_t per = (size_t)N * N * 4;
  int CB = 1;
  if (ws_size > used + per) {
    size_t c = (ws_size - used) / per;
    CB = c >= 8 ? 8 : (int)c;
    if (CB < 1) CB = 1;
  }

  cvt_w<<<dim3(64, 4), 256, 0, stream>>>(Wq, Wk, Wv, Wp, Wbf);
  gn_stats<<<512, 256, 0, stream>>>(x1, x2, stats);
  gn_apply<<<dim3(36, 8, 2), 256, 0, stream>>>(x1, x2, gamma, beta, stats, h1t,
                                               h2t);

  // projections: q1,k1 from h1t; q2,k2 from h2t; v from h1t
  gemm_bt<0, 0><<<dim3(18, 2, 8), 256, 0, stream>>>(
      h1t, Wbf + 0 * 65536, q1t, N, C, C, sH, 0, sH, bq, nullptr, 0, nullptr,
      nullptr, 0, 1.f);
  gemm_bt<0, 0><<<dim3(18, 2, 8), 256, 0, stream>>>(
      h1t, Wbf + 1 * 65536, k1t, N, C, C, sH, 0, sH, bk, nullptr, 0, nullptr,
      nullptr, 0, 1.f);
  gemm_bt<0, 0><<<dim3(18, 2, 8), 256, 0, stream>>>(
      h2t, Wbf + 0 * 65536, q2t, N, C, C, sH, 0, sH, bq, nullptr, 0, nullptr,
      nullptr, 0, 1.f);
  gemm_bt<0, 0><<<dim3(18, 2, 8), 256, 0, stream>>>(
      h2t, Wbf + 1 * 65536, k2t, N, C, C, sH, 0, sH, bk, nullptr, 0, nullptr,
      nullptr, 0, 1.f);
  gemm_bt<0, 1><<<dim3(2, 18, 8), 256, 0, stream>>>(
      Wbf + 2 * 65536, h1t, vB, C, N, C, 0, sH, sX, bv, nullptr, 0, nullptr,
      nullptr, 0, 1.f);

  const size_t half = (size_t)8 * C * N;
  for (int b0 = 0; b0 < 8; b0 += CB) {
    int nb = 8 - b0 < CB ? 8 - b0 : CB;
    // w1 = s * q1^T k1
    gemm_bt<0, 3><<<dim3(18, 18, nb), 256, 0, stream>>>(
        q1t + (size_t)b0 * sH, k1t + (size_t)b0 * sH, wbuf, N, N, C, sH, sH,
        sW, nullptr, nullptr, 0, nullptr, nullptr, 0, 0.0625f);
    rowstats<<<nb * N, 256, 0, stream>>>(wbuf, rmax + b0 * N, rsumr + b0 * N);
    // att_self = softmax(w1) @ v^T   -> attT [n][c]
    gemm_bt<1, 2><<<dim3(18, 2, nb), 256, 0, stream>>>(
        wbuf, vB + (size_t)b0 * sX, attT + (size_t)b0 * sH, N, C, N, sW, sX,
        sH, nullptr, nullptr, 0, rmax + b0 * N, rsumr + b0 * N, N, 1.f);
    // out_self = x1 + Wp @ att + bp
    gemm_bt<0, 5><<<dim3(2, 18, nb), 256, 0, stream>>>(
        Wbf + 3 * 65536, attT + (size_t)b0 * sH, out + (size_t)b0 * sX, C, N,
        C, 0, sH, sX, bp, x1 + (size_t)b0 * sX, sX, nullptr, nullptr, 0, 1.f);
    // w12 = w1 + s * q2^T k2  (in-place accumulate)
    gemm_bt<0, 4><<<dim3(18, 18, nb), 256, 0, stream>>>(
        q2t + (size_t)b0 * sH, k2t + (size_t)b0 * sH, wbuf, N, N, C, sH, sH,
        sW, nullptr, nullptr, 0, nullptr, nullptr, 0, 0.0625f);
    rowstats<<<nb * N, 256, 0, stream>>>(wbuf, rmax + b0 * N, rsumr + b0 * N);
    // att_cross = softmax(w1+w2) @ v^T
    gemm_bt<1, 2><<<dim3(18, 2, nb), 256, 0, stream>>>(
        wbuf, vB + (size_t)b0 * sX, attT + (size_t)b0 * sH, N, C, N, sW, sX,
        sH, nullptr, nullptr, 0, rmax + b0 * N, rsumr + b0 * N, N, 1.f);
    // out_cross = x1 + Wp @ att + bp
    gemm_bt<0, 5><<<dim3(2, 18, nb), 256, 0, stream>>>(
        Wbf + 3 * 65536, attT + (size_t)b0 * sH, out + half + (size_t)b0 * sX,
        C, N, C, 0, sH, sX, bp, x1 + (size_t)b0 * sX, sX, nullptr, nullptr, 0,
        1.f);
  }
}